// Round 5
// baseline (573.749 us; speedup 1.0000x reference)
//
#include <hip/hip_runtime.h>

// EMB=64, HEADS=8, TOK=10, CAP=32 (63-row tables), dim_q=dim_k=4116,
// dim_i=20, dim_h=dim_w=dim_d=16. S=4096; dim_q=20+4096.
//
// out[h][q][k] fp32:
//   q <  20           : 0
//   q >= 20, k <  20  : cross_s[h][k] * 0.125
//   q >= 20, k >= 20  : (row_s[h][i][l] + col_s[h][j][m] + dep_s[h][kk][n]) * (0.125/3)
//     r=q-20: i=r>>8, j=(r>>4)&15, kk=r&15;  c=k-20: l=c>>8, m=(c>>4)&15, n=c&15
//
// Fill: block (r,h), r<256, owns rows q0=20+16r..q0+15 = flat floats
// [82320+65856r, +65856) in the head plane. 82320*4 and 65856*4 are both
// multiples of 64 -> the whole block region is 64B-aligned and contiguous.
// Flat scan: chunk t (float4) at lane offset; per-lane k (column) and kk
// (local row) tracked incrementally (k0=4*tid, kk0=0; +1024 per iter with
// conditional wrap). Every 64-lane store = 16 full cache lines, no partials.
//
// tabs (ws floats): [0,160) cross (pre-scaled 0.125)
//                   [160,2208) row_s, [2208,4256) col_s, [4256,6304) dep_s

#define EMB 64
#define NHEADS 8
#define DIM_I 20
#define DIM_Q 4116
#define OFF_ROW 160
#define OFF_COL (160 + 2048)
#define OFF_DEP (160 + 4096)
#define N_DOTS 6304

typedef float v4f __attribute__((ext_vector_type(4)));

// One wave per dot product: lane c multiplies element c, butterfly-reduce.
__global__ __launch_bounds__(256) void tables_kernel(
    const float* __restrict__ enc_cross,  // [20][64]
    const float* __restrict__ enc_h,      // [63][64]
    const float* __restrict__ enc_w,
    const float* __restrict__ enc_d,
    const float* __restrict__ w_cross,    // [8][64]
    const float* __restrict__ w_h,
    const float* __restrict__ w_w,
    const float* __restrict__ w_d,
    float* __restrict__ tabs)
{
    const int wid  = (blockIdx.x * 256 + threadIdx.x) >> 6;
    const int lane = threadIdx.x & 63;
    if (wid >= N_DOTS) return;

    const float* wv;
    const float* ev;
    float scale;
    if (wid < 160) {
        const int h = wid / DIM_I;
        const int n = wid % DIM_I;
        wv = w_cross + h * EMB;
        ev = enc_cross + n * EMB;
        scale = 0.125f;
    } else {
        const int u = wid - 160;
        const int table = u >> 11;      // 0=row 1=col 2=dep
        const int v = u & 2047;
        const int h = v >> 8;
        const int i = (v >> 4) & 15;
        const int l = v & 15;
        const int ridx = l - i + 31;    // in [16,46], never clipped for dim 16
        if (table == 0)      { wv = w_h + h * EMB; ev = enc_h + ridx * EMB; }
        else if (table == 1) { wv = w_w + h * EMB; ev = enc_w + ridx * EMB; }
        else                 { wv = w_d + h * EMB; ev = enc_d + ridx * EMB; }
        scale = 0.125f / 3.0f;
    }

    float p = wv[lane] * ev[lane];
    #pragma unroll
    for (int off = 32; off >= 1; off >>= 1)
        p += __shfl_xor(p, off, 64);
    if (lane == 0) tabs[wid] = p * scale;
}

// grid (258, 8): x<256 -> content block (16 rows, flat-scanned);
// x in {256,257} -> zero rows q=0..19 (20580 chunks split 10304/10276 so
// both halves stay 64B-aligned).
__global__ __launch_bounds__(256) void fill_kernel(
    const float* __restrict__ tabs, float* __restrict__ out)
{
    const int h   = blockIdx.y;
    const int r   = blockIdx.x;
    const int tid = threadIdx.x;
    float* outh = out + (size_t)h * DIM_Q * DIM_Q;

    if (r >= 256) {
        const int b = r - 256;
        const int begin = b ? 10304 : 0;       // 10304*16 % 64 == 0
        const int end   = b ? 20580 : 10304;
        v4f* p = (v4f*)outh;
        const v4f z = {0.f, 0.f, 0.f, 0.f};
        for (int t = begin + tid; t < end; t += 256) p[t] = z;
        return;
    }

    __shared__ __align__(16) float A16[16];    // row_s[h][i][*]   (indexed by l)
    __shared__ __align__(16) float B16[16];    // col_s[h][j][*]   (indexed by m)
    __shared__ __align__(16) float C[256];     // dep_s[h][kk][n]
    __shared__ __align__(16) float cross[DIM_I];

    const int i = r >> 4;
    const int j = r & 15;
    if (tid < 16)                A16[tid]        = tabs[OFF_ROW + h * 256 + i * 16 + tid];
    else if (tid < 32)           B16[tid - 16]   = tabs[OFF_COL + h * 256 + j * 16 + (tid - 16)];
    else if (tid < 32 + DIM_I)   cross[tid - 32] = tabs[h * DIM_I + (tid - 32)];
    C[tid] = tabs[OFF_DEP + h * 256 + tid];
    __syncthreads();

    // block-flat region: floats [baseF, baseF+65856) of this head plane
    const int baseF = 82320 + 65856 * r;       // 64B-aligned in bytes
    v4f* p = (v4f*)(outh + baseF);

    int k  = 4 * tid;   // column index within row (block starts at a row start)
    int kk = 0;         // local row 0..15
    int t  = tid;

    #pragma unroll 4
    for (int it = 0; it < 64; ++it, t += 256) {
        const int c = (k >= DIM_I) ? (k - DIM_I) : 0;   // clamp keeps LDS idx >= 0
        const int l = c >> 8;
        const int m = (c >> 4) & 15;
        const int n = c & 15;
        v4f v = *(const v4f*)(C + kk * 16 + n) + (A16[l] + B16[m]);
        if (k < DIM_I) v = *(const v4f*)(cross + k);    // k in {0,4,8,12,16}
        p[t] = v;
        k += 1024;
        if (k >= DIM_Q) { k -= DIM_Q; ++kk; }
    }
    // tail: chunks 16384..16463 (80 of them); lane state already advanced
    if (tid < 80) {
        const int c = (k >= DIM_I) ? (k - DIM_I) : 0;
        const int l = c >> 8;
        const int m = (c >> 4) & 15;
        const int n = c & 15;
        v4f v = *(const v4f*)(C + kk * 16 + n) + (A16[l] + B16[m]);
        if (k < DIM_I) v = *(const v4f*)(cross + k);
        p[t] = v;
    }
}

extern "C" void kernel_launch(void* const* d_in, const int* in_sizes, int n_in,
                              void* d_out, int out_size, void* d_ws, size_t ws_size,
                              hipStream_t stream)
{
    const float* enc_cross = (const float*)d_in[0];
    const float* enc_h     = (const float*)d_in[1];
    const float* enc_w     = (const float*)d_in[2];
    const float* enc_d     = (const float*)d_in[3];
    const float* w_cross   = (const float*)d_in[4];
    const float* w_h       = (const float*)d_in[5];
    const float* w_w       = (const float*)d_in[6];
    const float* w_d       = (const float*)d_in[7];

    float* tabs = (float*)d_ws;   // 6304 floats

    tables_kernel<<<dim3((N_DOTS * 64 + 255) / 256), dim3(256), 0, stream>>>(
        enc_cross, enc_h, enc_w, enc_d, w_cross, w_h, w_w, w_d, tabs);

    fill_kernel<<<dim3(258, NHEADS), dim3(256), 0, stream>>>(
        tabs, (float*)d_out);
}